// Round 1
// baseline (4211.453 us; speedup 1.0000x reference)
//
#include <hip/hip_runtime.h>
#include <math.h>

#define T_STEPS 4096
#define NB 16          // batch
#define NH 256         // hidden
#define BH (NB * NH)   // 4096 floats per time step
#define DT_STEP 0.1f

// ---------------- expm via Taylor series ----------------
// S = I + A
__global__ __launch_bounds__(1024) void k_init_S(const float* __restrict__ A,
                                                 float* __restrict__ S) {
    int idx = blockIdx.x * 1024 + threadIdx.x;
    int i = idx >> 8, j = idx & 255;
    S[idx] = A[idx] + (i == j ? 1.0f : 0.0f);
}

// Pnew = (Pprev @ A) * invk ; S += Pnew
__global__ __launch_bounds__(256) void k_expm_term(const float* __restrict__ Pprev,
                                                   const float* __restrict__ A,
                                                   float* __restrict__ Pnew,
                                                   float* __restrict__ S,
                                                   float invk) {
    __shared__ float prow[256];
    int i = blockIdx.x, j = threadIdx.x;
    prow[j] = Pprev[i * 256 + j];
    __syncthreads();
    float acc = 0.f;
#pragma unroll 8
    for (int m = 0; m < 256; ++m) acc = fmaf(prow[m], A[m * 256 + j], acc);
    float v = acc * invk;
    Pnew[i * 256 + j] = v;
    S[i * 256 + j] += v;
}

// ---------------- row-blocked GEMM: Out[r][o] = sum_k X[r][k]*Wm[o][k] + bias[o]
// K = 256, O = 256, 16 rows per block, 256 threads. Safe for X == Out
// (rows staged to LDS before any write).
__global__ __launch_bounds__(256) void k_gemm_rows(const float* __restrict__ X,
                                                   const float* __restrict__ Wm,
                                                   const float* __restrict__ bias,
                                                   float* __restrict__ Out) {
    __shared__ float4 xs4[16][64];
    const int tid = threadIdx.x;
    const long r0 = (long)blockIdx.x * 16;
    float* xs = (float*)xs4;
#pragma unroll
    for (int rr = 0; rr < 16; ++rr) xs[rr * 256 + tid] = X[(r0 + rr) * 256 + tid];
    __syncthreads();

    float acc[16];
#pragma unroll
    for (int rr = 0; rr < 16; ++rr) acc[rr] = 0.f;

    const float4* wrow = (const float4*)(Wm + tid * 256);
    for (int d4 = 0; d4 < 64; ++d4) {
        float4 w = wrow[d4];
#pragma unroll
        for (int rr = 0; rr < 16; ++rr) {
            float4 xv = xs4[rr][d4];
            acc[rr] = fmaf(w.x, xv.x, acc[rr]);
            acc[rr] = fmaf(w.y, xv.y, acc[rr]);
            acc[rr] = fmaf(w.z, xv.z, acc[rr]);
            acc[rr] = fmaf(w.w, xv.w, acc[rr]);
        }
    }
    float b = bias[tid];
#pragma unroll
    for (int rr = 0; rr < 16; ++rr) Out[(r0 + rr) * 256 + tid] = acc[rr] + b;
}

// ---------------- sequential scan: one block per batch element ----------------
// 1024 threads: thread (i = tid&255, jc = tid>>8) owns W row i, K-chunk jc.
// W fragment (64 floats) held in VGPRs; h in LDS; 4-way partial reduce in LDS.
__global__ __launch_bounds__(1024) void k_scan(const float* __restrict__ u,
                                               const float* __restrict__ Wexp,
                                               float* __restrict__ hidden,
                                               float* __restrict__ hfin) {
    const int b = blockIdx.x;
    const int tid = threadIdx.x;
    const int i = tid & 255;
    const int jc = tid >> 8;

    __shared__ float4 h4s[64];          // h[256]
    __shared__ float part[4][256];
    float* hs = (float*)h4s;

    // W[i][jc*64 .. jc*64+63] into 16 float4 registers
    float4 wv[16];
    const float4* wp = (const float4*)(Wexp + i * 256 + jc * 64);
#pragma unroll
    for (int k = 0; k < 16; ++k) wv[k] = wp[k];

    if (jc == 0) hs[i] = 0.f;

    // u prefetch, distance 2 (u is L3-resident; hides latency under FMA loop)
    float u_cur = 0.f, u_nxt = 0.f;
    if (jc == 0) {
        u_cur = u[b * NH + i];
        u_nxt = u[BH + b * NH + i];
    }
    __syncthreads();

    const int hbase = jc * 16;
    for (int t = 0; t < T_STEPS; ++t) {
        float u_n2 = 0.f;
        if (jc == 0 && t + 2 < T_STEPS) u_n2 = u[(long)(t + 2) * BH + b * NH + i];

        float a0 = 0.f, a1 = 0.f, a2 = 0.f, a3 = 0.f;
#pragma unroll
        for (int k = 0; k < 16; ++k) {
            float4 hv = h4s[hbase + k];
            a0 = fmaf(wv[k].x, hv.x, a0);
            a1 = fmaf(wv[k].y, hv.y, a1);
            a2 = fmaf(wv[k].z, hv.z, a2);
            a3 = fmaf(wv[k].w, hv.w, a3);
        }
        part[jc][i] = (a0 + a1) + (a2 + a3);
        __syncthreads();

        if (jc == 0) {
            float y = (part[0][i] + part[1][i]) + (part[2][i] + part[3][i]);
            float hn = hs[i] + DT_STEP * tanhf(u_cur - y);
            hs[i] = hn;
            hidden[(long)t * BH + b * NH + i] = hn;
            if (t == T_STEPS - 1) hfin[b * NH + i] = hn;
            u_cur = u_nxt;
            u_nxt = u_n2;
        }
        __syncthreads();
    }
}

extern "C" void kernel_launch(void* const* d_in, const int* in_sizes, int n_in,
                              void* d_out, int out_size, void* d_ws, size_t ws_size,
                              hipStream_t stream) {
    const float* x     = (const float*)d_in[0];  // [T,B,D]
    const float* U_w   = (const float*)d_in[1];  // [H,D]
    const float* U_b   = (const float*)d_in[2];  // [H]
    const float* W_log = (const float*)d_in[3];  // [H,H]
    const float* c_w   = (const float*)d_in[4];  // [O,H]
    const float* c_b   = (const float*)d_in[5];  // [O]

    float* out    = (float*)d_out;
    float* hidden = out;                          // stage hidden in d_out, then in-place GEMM
    float* hfin   = out + (long)T_STEPS * BH;     // second output chunk

    float* ws = (float*)d_ws;
    float* S  = ws;                // 65536 floats: Wexp accumulator
    float* Pa = ws + 65536;
    float* Pb = ws + 2 * 65536;
    float* u  = ws + 3 * 65536;    // 16,777,216 floats

    // Wexp = expm(W_log), Taylor K=12 (||W_log||_2 ~ 0.32)
    k_init_S<<<64, 1024, 0, stream>>>(W_log, S);
    const float* prev = W_log;
    float* cur = Pa;
    for (int k = 2; k <= 12; ++k) {
        k_expm_term<<<256, 256, 0, stream>>>(prev, W_log, cur, S, 1.0f / (float)k);
        prev = cur;
        cur = (cur == Pa) ? Pb : Pa;
    }

    // u = x @ U_w^T + U_b
    k_gemm_rows<<<4096, 256, 0, stream>>>(x, U_w, U_b, u);

    // sequential recurrence, hidden -> d_out
    k_scan<<<NB, 1024, 0, stream>>>(u, S, hidden, hfin);

    // out = hidden @ c_w^T + c_b, in place
    k_gemm_rows<<<4096, 256, 0, stream>>>(hidden, c_w, c_b, hidden);
}